// Round 7
// baseline (115.224 us; speedup 1.0000x reference)
//
#include <hip/hip_runtime.h>
#include <hip/hip_bf16.h>
#include <cstddef>

// ---------------------------------------------------------------------------
// sparse_attn: transformer encoder block on levels 2 & 3.
// Round 7: barrier-free flash inner loop (chunked KV staging, wave-autonomous),
// interleaved u64 mask words, fused prep kernel.
// Rows 0..2047 = level2 (S=1024), rows 2048..2559 = level3 (S=256). R=2560.
// ---------------------------------------------------------------------------

typedef __attribute__((ext_vector_type(8))) short s16x8;
typedef __attribute__((ext_vector_type(4))) short s16x4;
typedef __attribute__((ext_vector_type(4))) float f32x4;
typedef __attribute__((ext_vector_type(2))) unsigned int u32x2;
typedef unsigned short ushort_t;
typedef unsigned long long u64;

#define RTOT 2560

__device__ inline unsigned short f2bf(float x) {
    union { __hip_bfloat16 h; unsigned short u; } cv;
    cv.h = __float2bfloat16(x);
    return cv.u;
}

// ---------------------------------------------------------------------------
// prep: fused weight-convert + mask-bit pack + input transpose.
// blocks 0..767      : weight fp32->bf16 (196608 float4s)
// blocks 768..5119   : mask bits (17408 waves, f32x4 per lane, 4 ballots)
//   lvl2 word layout: ub[(row*8 + chunk)*4 + j], bit i of word j = u2[row][chunk*256 + 4i + j]
//   lvl3 at ub+65536: ub[65536 + (row*2 + chunk)*4 + j]
// blocks 5120..7679  : f2/f3 NCHW -> [2560,256] fp32+bf16
// ---------------------------------------------------------------------------
__global__ __launch_bounds__(256) void prep(const float* __restrict__ wqkv,
                                            const float* __restrict__ wo,
                                            const float* __restrict__ wfc1,
                                            const float* __restrict__ wfc2,
                                            ushort_t* __restrict__ o1,
                                            ushort_t* __restrict__ o2,
                                            ushort_t* __restrict__ o3,
                                            ushort_t* __restrict__ o4,
                                            const float* __restrict__ u2,
                                            const float* __restrict__ u3,
                                            u64* __restrict__ ub,
                                            const float* __restrict__ f2,
                                            const float* __restrict__ f3,
                                            float* __restrict__ srcf,
                                            ushort_t* __restrict__ srcb) {
    int bid = blockIdx.x;
    int t = threadIdx.x;
    if (bid < 768) {
        int i = bid * 256 + t;
        const float* src; ushort_t* dst; int li;
        if (i < 49152)       { src = wqkv; dst = o1; li = i; }
        else if (i < 65536)  { src = wo;   dst = o2; li = i - 49152; }
        else if (i < 131072) { src = wfc1; dst = o3; li = i - 65536; }
        else                 { src = wfc2; dst = o4; li = i - 131072; }
        f32x4 v = ((const f32x4*)src)[li];
        s16x4 r;
        r[0] = (short)f2bf(v[0]); r[1] = (short)f2bf(v[1]);
        r[2] = (short)f2bf(v[2]); r[3] = (short)f2bf(v[3]);
        ((s16x4*)dst)[li] = r;
    } else if (bid < 5120) {
        int gw = ((bid - 768) * 256 + t) >> 6;   // 0..17407
        int lane = t & 63;
        const float* p;
        u64* dst;
        if (gw < 16384) {
            int row = gw >> 3, chunk = gw & 7;
            p = &u2[(size_t)row * 2048 + chunk * 256 + lane * 4];
            dst = &ub[(size_t)gw * 4];
        } else {
            int lw = gw - 16384;
            int row = lw >> 1, chunk = lw & 1;
            p = &u3[(size_t)row * 512 + chunk * 256 + lane * 4];
            dst = &ub[65536 + (size_t)lw * 4];
        }
        f32x4 v = *(const f32x4*)p;
        u64 b0 = __ballot(v[0] >= 0.1f);
        u64 b1 = __ballot(v[1] >= 0.1f);
        u64 b2 = __ballot(v[2] >= 0.1f);
        u64 b3 = __ballot(v[3] >= 0.1f);
        if (lane < 4) {
            u64 bb = (lane == 0) ? b0 : (lane == 1) ? b1 : (lane == 2) ? b2 : b3;
            dst[lane] = bb;
        }
    } else {
        int idx = (bid - 5120) * 256 + t;        // over 2560*256
        int r = idx >> 8, c = idx & 255;
        float v;
        if (r < 2048) {
            int n = r >> 10, hw = r & 1023;
            v = f2[(size_t)((n * 256 + c) << 10) + hw];
        } else {
            int rl = r - 2048;
            int n = rl >> 8, hw = rl & 255;
            v = f3[(size_t)((n * 256 + c) << 8) + hw];
        }
        srcf[idx] = v;
        srcb[idx] = f2bf(v);
    }
}

// combined [2560,256] -> out2 (2,256,32,32) and out3 (2,256,16,16)
__global__ __launch_bounds__(256) void lc_out(const float* __restrict__ y,
                                              float* __restrict__ out2,
                                              float* __restrict__ out3) {
    int idx = blockIdx.x * 256 + threadIdx.x;
    if (idx < 524288) {
        int n = idx >> 18;
        int rem = idx & 262143;
        int c = rem >> 10, hw = rem & 1023;
        out2[idx] = y[(size_t)(n * 1024 + hw) * 256 + c];
    } else {
        int li = idx - 524288;
        int n = li >> 16;
        int rem = li & 65535;
        int c = rem >> 8, hw = rem & 255;
        out3[li] = y[(size_t)(2048 + n * 256 + hw) * 256 + c];
    }
}

// ---------------------------------------------------------------------------
// bf16 MFMA GEMM, tile 32x32, 128 threads (2 waves), K-step 64, dbuf LDS.
// EPI: 0=bias, 1=bias+relu, 2=bias+res(f32), 3=bias then q-scale (n<256)
// ---------------------------------------------------------------------------
#define ASTR 72

template <int EPI, int OUTBF>
__global__ __launch_bounds__(128) void gemm32(const ushort_t* __restrict__ A,
                                              const ushort_t* __restrict__ W,
                                              const float* __restrict__ bias,
                                              const float* __restrict__ res,
                                              void* __restrict__ outv,
                                              int M, int N, int K) {
    __shared__ __align__(16) ushort_t As[2][32 * ASTR];
    __shared__ __align__(16) ushort_t Ws[2][32 * ASTR];

    const int t = threadIdx.x;
    const int w = t >> 6, l = t & 63;
    const int c = l & 15, g = l >> 4;
    const int m0 = blockIdx.y * 32, n0 = blockIdx.x * 32;
    const int srow = t >> 3;
    const int cg8 = (t & 7) * 8;

    const ushort_t* Aip0 = &A[(size_t)(m0 + srow) * K + cg8];
    const ushort_t* Aip1 = &A[(size_t)(m0 + 16 + srow) * K + cg8];
    const ushort_t* Wip0 = &W[(size_t)(n0 + srow) * K + cg8];
    const ushort_t* Wip1 = &W[(size_t)(n0 + 16 + srow) * K + cg8];

    s16x8 ra0 = *(const s16x8*)Aip0;
    s16x8 ra1 = *(const s16x8*)Aip1;
    s16x8 rw0 = *(const s16x8*)Wip0;
    s16x8 rw1 = *(const s16x8*)Wip1;
    *(s16x8*)&As[0][srow * ASTR + cg8] = ra0;
    *(s16x8*)&As[0][(16 + srow) * ASTR + cg8] = ra1;
    *(s16x8*)&Ws[0][srow * ASTR + cg8] = rw0;
    *(s16x8*)&Ws[0][(16 + srow) * ASTR + cg8] = rw1;
    __syncthreads();

    f32x4 acc[2] = {{0.f, 0.f, 0.f, 0.f}, {0.f, 0.f, 0.f, 0.f}};
    const int nsteps = K >> 6;

    for (int ks = 0; ks < nsteps; ++ks) {
        const int b = ks & 1;
        const bool pf = (ks + 1 < nsteps);
        if (pf) {
            int ko = (ks + 1) << 6;
            ra0 = *(const s16x8*)(Aip0 + ko);
            ra1 = *(const s16x8*)(Aip1 + ko);
            rw0 = *(const s16x8*)(Wip0 + ko);
            rw1 = *(const s16x8*)(Wip1 + ko);
        }
#pragma unroll
        for (int kt = 0; kt < 2; ++kt) {
            s16x8 af = *(const s16x8*)&As[b][(16 * w + c) * ASTR + kt * 32 + 8 * g];
            s16x8 wf0 = *(const s16x8*)&Ws[b][c * ASTR + kt * 32 + 8 * g];
            s16x8 wf1 = *(const s16x8*)&Ws[b][(16 + c) * ASTR + kt * 32 + 8 * g];
            acc[0] = __builtin_amdgcn_mfma_f32_16x16x32_bf16(af, wf0, acc[0], 0, 0, 0);
            acc[1] = __builtin_amdgcn_mfma_f32_16x16x32_bf16(af, wf1, acc[1], 0, 0, 0);
        }
        if (pf) {
            int nb = b ^ 1;
            *(s16x8*)&As[nb][srow * ASTR + cg8] = ra0;
            *(s16x8*)&As[nb][(16 + srow) * ASTR + cg8] = ra1;
            *(s16x8*)&Ws[nb][srow * ASTR + cg8] = rw0;
            *(s16x8*)&Ws[nb][(16 + srow) * ASTR + cg8] = rw1;
        }
        __syncthreads();
    }

#pragma unroll
    for (int nt = 0; nt < 2; ++nt) {
        int n = n0 + 16 * nt + c;
        float bv = bias[n];
        float sc = 1.f;
        if (EPI == 3) sc = (n < 256) ? 0.17677669529663687f : 1.f;
#pragma unroll
        for (int r = 0; r < 4; ++r) {
            int m = m0 + 16 * w + 4 * g + r;
            float v = acc[nt][r] + bv;
            if (EPI == 1) v = fmaxf(v, 0.f);
            if (EPI == 2) v += res[(size_t)m * N + n];
            if (EPI == 3) v *= sc;
            if (OUTBF) ((ushort_t*)outv)[(size_t)m * N + n] = f2bf(v);
            else ((float*)outv)[(size_t)m * N + n] = v;
        }
    }
}

// ---------------------------------------------------------------------------
// Chunked flash attention: block = (64 q-rows, head, 256-key chunk), 4 waves.
// Stage Q/K/V for the whole chunk ONCE, then waves sweep 4x64-key subtiles
// with no barriers (private P scratch + accumulators).
// lvl2: blocks 0..2047   = qt(32) x h(8) x chunk(8)
// lvl3: blocks 2048..2175 = qt(8)  x h(8) x chunk(2)
// ---------------------------------------------------------------------------
#define QS 40
#define KS 40
#define VS 264   // vts row stride: 256 keys + 8 pad
#define PS 72
#define OS 68

__global__ __launch_bounds__(256) void flash_chunk(const ushort_t* __restrict__ qkvb,
                                                   const u64* __restrict__ ubits,
                                                   float* __restrict__ Opart,
                                                   float2* __restrict__ ml) {
    __shared__ __align__(16) ushort_t qs[64 * QS];
    __shared__ __align__(16) ushort_t ks[256 * KS];
    __shared__ __align__(16) ushort_t vts[32 * VS];
    __shared__ __align__(16) ushort_t ps[4 * 16 * PS];
    float* os = (float*)ks;   // aliased after compute (barrier-guarded)

    const int bx = blockIdx.x;
    int qt, h, split, sshift, rowbase, chunks;
    const u64* ub;
    if (bx < 2048) {
        qt = bx & 31; h = (bx >> 5) & 7; split = bx >> 8;
        sshift = 10; rowbase = 0; chunks = 8; ub = ubits;
    } else {
        int lo = bx - 2048;
        qt = lo & 7; h = (lo >> 3) & 7; split = lo >> 6;
        sshift = 8; rowbase = 2048; chunks = 2; ub = ubits + 65536;
    }
    const int t = threadIdx.x;
    const int w = t >> 6;
    const int l = t & 63;
    const int c = l & 15;
    const int g = l >> 4;
    const int smask = (1 << sshift) - 1;

    const int q0g = rowbase + qt * 64;       // global first q row
    const int kbase = rowbase + split * 256; // global first kv row of chunk

    // ---- stage Q (64x32), K (256x32), V^T (32x256) ----
    {
        int srow = t >> 2, sc8 = (t & 3) * 8;
        *(s16x8*)&qs[srow * QS + sc8] =
            *(const s16x8*)&qkvb[(size_t)(q0g + srow) * 768 + h * 32 + sc8];
#pragma unroll
        for (int i = 0; i < 4; ++i) {
            int row = 64 * i + srow;
            size_t base = (size_t)(kbase + row) * 768 + h * 32 + sc8;
            *(s16x8*)&ks[row * KS + sc8] = *(const s16x8*)&qkvb[base + 256];
            s16x8 vreg = *(const s16x8*)&qkvb[base + 512];
#pragma unroll
            for (int j = 0; j < 8; ++j)
                vts[(sc8 + j) * VS + row] = (ushort_t)vreg[j];
        }
    }
    __syncthreads();

    const s16x8 qf = *(const s16x8*)&qs[(16 * w + c) * QS + 8 * g];
    const int ql = qt * 64 + 16 * w + c;     // level-local q row
    const int qp = ql & smask, qfr = ql >> sshift;

    // 4 interleaved mask words for this (row, chunk)
    const u64* bp = &ub[((size_t)ql * chunks + split) * 4];
    u64 wr0 = bp[0], wr1 = bp[1], wr2 = bp[2], wr3 = bp[3];

    ushort_t* psw = &ps[w * 16 * PS];

    f32x4 oacc0 = {0.f, 0.f, 0.f, 0.f};
    f32x4 oacc1 = {0.f, 0.f, 0.f, 0.f};
    float mold = -3e38f, lrun = 0.f;
    const f32x4 zc = {0.f, 0.f, 0.f, 0.f};

#pragma unroll
    for (int st = 0; st < 4; ++st) {
        // ---- S^T = K · Q^T : 4 MFMAs (keys 64*st .. +63) ----
        f32x4 sacc[4];
#pragma unroll
        for (int nt = 0; nt < 4; ++nt) {
            s16x8 kf = *(const s16x8*)&ks[(64 * st + 16 * nt + c) * KS + 8 * g];
            sacc[nt] = __builtin_amdgcn_mfma_f32_16x16x32_bf16(kf, qf, zc, 0, 0, 0);
        }

        // ---- mask + per-lane online softmax ----
        float sv[4][4];
        float m = -3e38f;
#pragma unroll
        for (int nt = 0; nt < 4; ++nt) {
            unsigned sh = 16 * st + 4 * nt + g;
            int kg = split * 256 + 64 * st + 16 * nt + 4 * g;  // level-local key base
#pragma unroll
            for (int r = 0; r < 4; ++r) {
                u64 wrd = (r == 0) ? wr0 : (r == 1) ? wr1 : (r == 2) ? wr2 : wr3;
                int k = kg + r;
                float s = sacc[nt][r]
                        + ((wrd >> sh) & 1 ? 1.f : 0.f)
                        + ((k & smask) == qp ? 1.f : 0.f)
                        + ((k >> sshift) == qfr ? 1.f : 0.f);
                sv[nt][r] = s;
                m = fmaxf(m, s);
            }
        }
        m = fmaxf(m, __shfl_xor(m, 16));
        m = fmaxf(m, __shfl_xor(m, 32));
        float newm = fmaxf(mold, m);
        float fac = __expf(mold - newm);
        mold = newm;

        float sum = 0.f;
#pragma unroll
        for (int nt = 0; nt < 4; ++nt) {
            float p0 = __expf(sv[nt][0] - newm);
            float p1 = __expf(sv[nt][1] - newm);
            float p2 = __expf(sv[nt][2] - newm);
            float p3 = __expf(sv[nt][3] - newm);
            sum += (p0 + p1) + (p2 + p3);
            u32x2 pk;
            pk[0] = ((unsigned)f2bf(p1) << 16) | f2bf(p0);
            pk[1] = ((unsigned)f2bf(p3) << 16) | f2bf(p2);
            *(u32x2*)&psw[c * PS + 16 * nt + 4 * g] = pk;
        }
        sum += __shfl_xor(sum, 16);
        sum += __shfl_xor(sum, 32);
        lrun = lrun * fac + sum;
        oacc0 *= fac;
        oacc1 *= fac;

        // ---- O^T += V^T · P^T : 4 MFMAs ----
#pragma unroll
        for (int kc = 0; kc < 2; ++kc) {
            s16x8 pfr = *(const s16x8*)&psw[c * PS + 32 * kc + 8 * g];
            int kofs = 64 * st + 32 * kc + 8 * g;
            s16x8 vf0 = *(const s16x8*)&vts[c * VS + kofs];
            s16x8 vf1 = *(const s16x8*)&vts[(16 + c) * VS + kofs];
            oacc0 = __builtin_amdgcn_mfma_f32_16x16x32_bf16(vf0, pfr, oacc0, 0, 0, 0);
            oacc1 = __builtin_amdgcn_mfma_f32_16x16x32_bf16(vf1, pfr, oacc1, 0, 0, 0);
        }
    }

    // (m, l) once per q-row
    if (g == 0) {
        int q = q0g + 16 * w + c;
        ml[((size_t)split * RTOT + q) * 8 + h] = make_float2(mold, lrun);
    }

    // unnormalized partial O via LDS transpose (os aliases ks)
    __syncthreads();
#pragma unroll
    for (int r = 0; r < 4; ++r) {
        os[(4 * g + r) * OS + 16 * w + c] = oacc0[r];
        os[(16 + 4 * g + r) * OS + 16 * w + c] = oacc1[r];
    }
    __syncthreads();
    {
        int r = t >> 2, d0 = (t & 3) * 8;
        float* op = &Opart[((size_t)split * RTOT + q0g + r) * 256 + h * 32 + d0];
        f32x4 w0, w1;
#pragma unroll
        for (int i = 0; i < 4; ++i) w0[i] = os[(d0 + i) * OS + r];
#pragma unroll
        for (int i = 0; i < 4; ++i) w1[i] = os[(d0 + 4 + i) * OS + r];
        *(f32x4*)op = w0;
        *(f32x4*)(op + 4) = w1;
    }
}

// merge split partials -> bf16 attention output [2560,256]
// lvl2 rows: 8 splits; lvl3 rows: 2 splits
__global__ __launch_bounds__(256) void flash_merge(const float* __restrict__ Opart,
                                                   const float2* __restrict__ ml,
                                                   ushort_t* __restrict__ obuf) {
    int r = blockIdx.x, t = threadIdx.x;
    int h = t >> 5;
    int ns = (r < 2048) ? 8 : 2;
    float ms = -3e38f;
    float2 mls[8];
#pragma unroll 8
    for (int s = 0; s < ns; ++s) {
        mls[s] = ml[((size_t)s * RTOT + r) * 8 + h];
        ms = fmaxf(ms, mls[s].x);
    }
    float denom = 0.f;
    float wgt[8];
#pragma unroll 8
    for (int s = 0; s < ns; ++s) {
        wgt[s] = __expf(mls[s].x - ms);
        denom += wgt[s] * mls[s].y;
    }
    size_t idx = (size_t)r * 256 + t;
    const size_t stride = (size_t)RTOT * 256;
    float v = 0.f;
#pragma unroll 8
    for (int s = 0; s < ns; ++s) v += wgt[s] * Opart[idx + s * stride];
    obuf[idx] = f2bf(v / denom);
}

// LayerNorm over C=256, one block per row; optional bf16 copy
template <int WB>
__global__ __launch_bounds__(256) void ln_kernel(const float* __restrict__ in,
                                                 const float* __restrict__ g,
                                                 const float* __restrict__ b,
                                                 float* __restrict__ outf,
                                                 ushort_t* __restrict__ outb) {
    __shared__ float red[256];
    int row = blockIdx.x, t = threadIdx.x;
    float v = in[(size_t)row * 256 + t];
    red[t] = v;
    __syncthreads();
    for (int s = 128; s > 0; s >>= 1) {
        if (t < s) red[t] += red[t + s];
        __syncthreads();
    }
    float mean = red[0] * (1.f / 256.f);
    __syncthreads();
    float d = v - mean;
    red[t] = d * d;
    __syncthreads();
    for (int s = 128; s > 0; s >>= 1) {
        if (t < s) red[t] += red[t + s];
        __syncthreads();
    }
    float var = red[0] * (1.f / 256.f);
    float r = d * rsqrtf(var + 1e-5f) * g[t] + b[t];
    outf[(size_t)row * 256 + t] = r;
    if (WB) outb[(size_t)row * 256 + t] = f2bf(r);
}

// ---------------------------------------------------------------------------

extern "C" void kernel_launch(void* const* d_in, const int* in_sizes, int n_in,
                              void* d_out, int out_size, void* d_ws, size_t ws_size,
                              hipStream_t stream) {
    const float* f0 = (const float*)d_in[0];
    const float* f1 = (const float*)d_in[1];
    const float* f2 = (const float*)d_in[2];
    const float* f3 = (const float*)d_in[3];
    const float* u2 = (const float*)d_in[4];
    const float* u3 = (const float*)d_in[5];
    const float* Wqkv = (const float*)d_in[6];
    const float* bqkv = (const float*)d_in[7];
    const float* Wo   = (const float*)d_in[8];
    const float* bo   = (const float*)d_in[9];
    const float* g1   = (const float*)d_in[10];
    const float* b1   = (const float*)d_in[11];
    const float* Wfc1 = (const float*)d_in[12];
    const float* bfc1 = (const float*)d_in[13];
    const float* Wfc2 = (const float*)d_in[14];
    const float* bfc2 = (const float*)d_in[15];
    const float* g2   = (const float*)d_in[16];
    const float* b2   = (const float*)d_in[17];

    float* out = (float*)d_out;
    float* ws = (float*)d_ws;

    // bf16 weights
    ushort_t* wqkv = (ushort_t*)ws;             // 196608 us
    ushort_t* wo   = (ushort_t*)(ws + 98304);   // 65536 us
    ushort_t* wfc1 = (ushort_t*)(ws + 131072);  // 262144 us
    ushort_t* wfc2 = (ushort_t*)(ws + 262144);  // 262144 us

    // scratch (floats), R = 2560 rows
    float* sc = ws + 393216;
    float*    src_f32 = sc;                          // [0, 655360)
    ushort_t* qkvb    = (ushort_t*)(sc + 655360);    // 2560*768 us -> ends 1638400
    ushort_t* obuf    = (ushort_t*)(sc + 1638400);   // 2560*256 us (src_bf alias)
    ushort_t* src_bf  = obuf;
    float*    t1      = sc + 1966080;                // 655360
    float*    x_f32   = sc + 2621440;                // 655360 (ubits alias)
    u64*      ubits   = (u64*)x_f32;                 // 69632 u64 = 139264 floats
    ushort_t* x_bf    = (ushort_t*)(sc + 3276800);   // 2560*256 us
    float2*   ml      = (float2*)(sc + 3604480);     // 8*2560*8 f2 = 327680 floats
    float*    Opart   = sc + 3932160;                // 8*2560*256 f32 = 5242880
    ushort_t* h_bf    = (ushort_t*)Opart;            // 2560*1024 us (alias)
    float*    y       = src_f32;                     // reuse

    prep<<<7680, 256, 0, stream>>>(Wqkv, Wo, Wfc1, Wfc2, wqkv, wo, wfc1, wfc2,
                                   u2, u3, ubits, f2, f3, src_f32, src_bf);

    hipMemcpyAsync(out, f0, (size_t)3276800 * 4, hipMemcpyDeviceToDevice, stream);
    hipMemcpyAsync(out + 3276800, f1, (size_t)819200 * 4, hipMemcpyDeviceToDevice, stream);

    gemm32<3, 1><<<dim3(24, 80), 128, 0, stream>>>(
        src_bf, wqkv, bqkv, nullptr, qkvb, RTOT, 768, 256);
    flash_chunk<<<2176, 256, 0, stream>>>(qkvb, ubits, Opart, ml);
    flash_merge<<<2560, 256, 0, stream>>>(Opart, ml, obuf);
    gemm32<2, 0><<<dim3(8, 80), 128, 0, stream>>>(
        obuf, wo, bo, src_f32, t1, RTOT, 256, 256);
    ln_kernel<1><<<2560, 256, 0, stream>>>(t1, g1, b1, x_f32, x_bf);
    gemm32<1, 1><<<dim3(32, 80), 128, 0, stream>>>(
        x_bf, wfc1, bfc1, nullptr, h_bf, RTOT, 1024, 256);
    gemm32<2, 0><<<dim3(8, 80), 128, 0, stream>>>(
        h_bf, wfc2, bfc2, x_f32, t1, RTOT, 256, 1024);
    ln_kernel<0><<<2560, 256, 0, stream>>>(t1, g2, b2, y, nullptr);
    lc_out<<<2560, 256, 0, stream>>>(y, out + 4096000, out + 4620288);
}

// Round 8
// 96.729 us; speedup vs baseline: 1.1912x; 1.1912x over previous
//
#include <hip/hip_runtime.h>
#include <hip/hip_bf16.h>
#include <cstddef>

// ---------------------------------------------------------------------------
// sparse_attn: transformer encoder block on levels 2 & 3.
// Round 8: R5 flash skeleton + bitmask + VS=66 bank fix + bf16 Opart;
// 64x64 MFMA GEMM for qkv/fc1. Rows 0..2047 lvl2, 2048..2559 lvl3.
// ---------------------------------------------------------------------------

typedef __attribute__((ext_vector_type(8))) short s16x8;
typedef __attribute__((ext_vector_type(4))) short s16x4;
typedef __attribute__((ext_vector_type(4))) float f32x4;
typedef __attribute__((ext_vector_type(2))) unsigned int u32x2;
typedef unsigned short ushort_t;
typedef unsigned long long u64;

#define RTOT 2560

__device__ inline unsigned short f2bf(float x) {
    union { __hip_bfloat16 h; unsigned short u; } cv;
    cv.h = __float2bfloat16(x);
    return cv.u;
}
__device__ inline float bf2f(unsigned short u) {
    union { unsigned int i; float f; } cv;
    cv.i = ((unsigned int)u) << 16;
    return cv.f;
}

// ---------------------------------------------------------------------------
// prep: blocks 0..767 weights fp32->bf16; 768..18175 mask bits (1 u64/wave,
// linear: word gw covers 64 consecutive u elements; lvl2 words 0..65535,
// lvl3 65536..69631); 18176..20735 f2/f3 NCHW -> [2560,256] fp32+bf16.
// ---------------------------------------------------------------------------
__global__ __launch_bounds__(256) void prep(const float* __restrict__ wqkv,
                                            const float* __restrict__ wo,
                                            const float* __restrict__ wfc1,
                                            const float* __restrict__ wfc2,
                                            ushort_t* __restrict__ o1,
                                            ushort_t* __restrict__ o2,
                                            ushort_t* __restrict__ o3,
                                            ushort_t* __restrict__ o4,
                                            const float* __restrict__ u2,
                                            const float* __restrict__ u3,
                                            u64* __restrict__ ub,
                                            const float* __restrict__ f2,
                                            const float* __restrict__ f3,
                                            float* __restrict__ srcf,
                                            ushort_t* __restrict__ srcb) {
    int bid = blockIdx.x;
    int t = threadIdx.x;
    if (bid < 768) {
        int i = bid * 256 + t;
        const float* src; ushort_t* dst; int li;
        if (i < 49152)       { src = wqkv; dst = o1; li = i; }
        else if (i < 65536)  { src = wo;   dst = o2; li = i - 49152; }
        else if (i < 131072) { src = wfc1; dst = o3; li = i - 65536; }
        else                 { src = wfc2; dst = o4; li = i - 131072; }
        f32x4 v = ((const f32x4*)src)[li];
        s16x4 r;
        r[0] = (short)f2bf(v[0]); r[1] = (short)f2bf(v[1]);
        r[2] = (short)f2bf(v[2]); r[3] = (short)f2bf(v[3]);
        ((s16x4*)dst)[li] = r;
    } else if (bid < 18176) {
        int gw = ((bid - 768) * 256 + t) >> 6;   // 0..69631
        int lane = t & 63;
        float v;
        if (gw < 65536) v = u2[(size_t)gw * 64 + lane];
        else            v = u3[(size_t)(gw - 65536) * 64 + lane];
        u64 b = __ballot(v >= 0.1f);
        if (lane == 0) ub[gw] = b;
    } else {
        int idx = (bid - 18176) * 256 + t;       // over 2560*256
        int r = idx >> 8, c = idx & 255;
        float v;
        if (r < 2048) {
            int n = r >> 10, hw = r & 1023;
            v = f2[(size_t)((n * 256 + c) << 10) + hw];
        } else {
            int rl = r - 2048;
            int n = rl >> 8, hw = rl & 255;
            v = f3[(size_t)((n * 256 + c) << 8) + hw];
        }
        srcf[idx] = v;
        srcb[idx] = f2bf(v);
    }
}

// combined [2560,256] -> out2 (2,256,32,32) and out3 (2,256,16,16)
__global__ __launch_bounds__(256) void lc_out(const float* __restrict__ y,
                                              float* __restrict__ out2,
                                              float* __restrict__ out3) {
    int idx = blockIdx.x * 256 + threadIdx.x;
    if (idx < 524288) {
        int n = idx >> 18;
        int rem = idx & 262143;
        int c = rem >> 10, hw = rem & 1023;
        out2[idx] = y[(size_t)(n * 1024 + hw) * 256 + c];
    } else {
        int li = idx - 524288;
        int n = li >> 16;
        int rem = li & 65535;
        int c = rem >> 8, hw = rem & 255;
        out3[li] = y[(size_t)(2048 + n * 256 + hw) * 256 + c];
    }
}

#define ASTR 72

// ---------------------------------------------------------------------------
// bf16 MFMA GEMM, tile 32x32, 128 threads (2 waves). For N=256 GEMMs.
// EPI: 0=bias, 1=bias+relu, 2=bias+res(f32), 3=bias then q-scale (n<256)
// ---------------------------------------------------------------------------
template <int EPI, int OUTBF>
__global__ __launch_bounds__(128) void gemm32(const ushort_t* __restrict__ A,
                                              const ushort_t* __restrict__ W,
                                              const float* __restrict__ bias,
                                              const float* __restrict__ res,
                                              void* __restrict__ outv,
                                              int M, int N, int K) {
    __shared__ __align__(16) ushort_t As[2][32 * ASTR];
    __shared__ __align__(16) ushort_t Ws[2][32 * ASTR];

    const int t = threadIdx.x;
    const int w = t >> 6, l = t & 63;
    const int c = l & 15, g = l >> 4;
    const int m0 = blockIdx.y * 32, n0 = blockIdx.x * 32;
    const int srow = t >> 3;
    const int cg8 = (t & 7) * 8;

    const ushort_t* Aip0 = &A[(size_t)(m0 + srow) * K + cg8];
    const ushort_t* Aip1 = &A[(size_t)(m0 + 16 + srow) * K + cg8];
    const ushort_t* Wip0 = &W[(size_t)(n0 + srow) * K + cg8];
    const ushort_t* Wip1 = &W[(size_t)(n0 + 16 + srow) * K + cg8];

    s16x8 ra0 = *(const s16x8*)Aip0;
    s16x8 ra1 = *(const s16x8*)Aip1;
    s16x8 rw0 = *(const s16x8*)Wip0;
    s16x8 rw1 = *(const s16x8*)Wip1;
    *(s16x8*)&As[0][srow * ASTR + cg8] = ra0;
    *(s16x8*)&As[0][(16 + srow) * ASTR + cg8] = ra1;
    *(s16x8*)&Ws[0][srow * ASTR + cg8] = rw0;
    *(s16x8*)&Ws[0][(16 + srow) * ASTR + cg8] = rw1;
    __syncthreads();

    f32x4 acc[2] = {{0.f, 0.f, 0.f, 0.f}, {0.f, 0.f, 0.f, 0.f}};
    const int nsteps = K >> 6;

    for (int ks = 0; ks < nsteps; ++ks) {
        const int b = ks & 1;
        const bool pf = (ks + 1 < nsteps);
        if (pf) {
            int ko = (ks + 1) << 6;
            ra0 = *(const s16x8*)(Aip0 + ko);
            ra1 = *(const s16x8*)(Aip1 + ko);
            rw0 = *(const s16x8*)(Wip0 + ko);
            rw1 = *(const s16x8*)(Wip1 + ko);
        }
#pragma unroll
        for (int kt = 0; kt < 2; ++kt) {
            s16x8 af = *(const s16x8*)&As[b][(16 * w + c) * ASTR + kt * 32 + 8 * g];
            s16x8 wf0 = *(const s16x8*)&Ws[b][c * ASTR + kt * 32 + 8 * g];
            s16x8 wf1 = *(const s16x8*)&Ws[b][(16 + c) * ASTR + kt * 32 + 8 * g];
            acc[0] = __builtin_amdgcn_mfma_f32_16x16x32_bf16(af, wf0, acc[0], 0, 0, 0);
            acc[1] = __builtin_amdgcn_mfma_f32_16x16x32_bf16(af, wf1, acc[1], 0, 0, 0);
        }
        if (pf) {
            int nb = b ^ 1;
            *(s16x8*)&As[nb][srow * ASTR + cg8] = ra0;
            *(s16x8*)&As[nb][(16 + srow) * ASTR + cg8] = ra1;
            *(s16x8*)&Ws[nb][srow * ASTR + cg8] = rw0;
            *(s16x8*)&Ws[nb][(16 + srow) * ASTR + cg8] = rw1;
        }
        __syncthreads();
    }

#pragma unroll
    for (int nt = 0; nt < 2; ++nt) {
        int n = n0 + 16 * nt + c;
        float bv = bias[n];
        float sc = 1.f;
        if (EPI == 3) sc = (n < 256) ? 0.17677669529663687f : 1.f;
#pragma unroll
        for (int r = 0; r < 4; ++r) {
            int m = m0 + 16 * w + 4 * g + r;
            float v = acc[nt][r] + bv;
            if (EPI == 1) v = fmaxf(v, 0.f);
            if (EPI == 2) v += res[(size_t)m * N + n];
            if (EPI == 3) v *= sc;
            if (OUTBF) ((ushort_t*)outv)[(size_t)m * N + n] = f2bf(v);
            else ((float*)outv)[(size_t)m * N + n] = v;
        }
    }
}

// ---------------------------------------------------------------------------
// bf16 MFMA GEMM, tile 64x64, 256 threads (4 waves), 8 MFMA/K-step/wave.
// Wave w: m-half mh=w>>1, n-half nh=w&1 (32x32 each, acc[2][2]).
// ---------------------------------------------------------------------------
template <int EPI, int OUTBF>
__global__ __launch_bounds__(256) void gemm64(const ushort_t* __restrict__ A,
                                              const ushort_t* __restrict__ W,
                                              const float* __restrict__ bias,
                                              const float* __restrict__ res,
                                              void* __restrict__ outv,
                                              int M, int N, int K) {
    __shared__ __align__(16) ushort_t As[2][64 * ASTR];
    __shared__ __align__(16) ushort_t Ws[2][64 * ASTR];

    const int t = threadIdx.x;
    const int w = t >> 6, l = t & 63;
    const int c = l & 15, g = l >> 4;
    const int mh = w >> 1, nh = w & 1;
    const int m0 = blockIdx.y * 64, n0 = blockIdx.x * 64;
    const int srow = t >> 3;          // 0..31
    const int cg8 = (t & 7) * 8;

    const ushort_t* Aip0 = &A[(size_t)(m0 + srow) * K + cg8];
    const ushort_t* Aip1 = &A[(size_t)(m0 + 32 + srow) * K + cg8];
    const ushort_t* Wip0 = &W[(size_t)(n0 + srow) * K + cg8];
    const ushort_t* Wip1 = &W[(size_t)(n0 + 32 + srow) * K + cg8];

    s16x8 ra0 = *(const s16x8*)Aip0;
    s16x8 ra1 = *(const s16x8*)Aip1;
    s16x8 rw0 = *(const s16x8*)Wip0;
    s16x8 rw1 = *(const s16x8*)Wip1;
    *(s16x8*)&As[0][srow * ASTR + cg8] = ra0;
    *(s16x8*)&As[0][(32 + srow) * ASTR + cg8] = ra1;
    *(s16x8*)&Ws[0][srow * ASTR + cg8] = rw0;
    *(s16x8*)&Ws[0][(32 + srow) * ASTR + cg8] = rw1;
    __syncthreads();

    f32x4 acc[2][2] = {{{0.f,0.f,0.f,0.f},{0.f,0.f,0.f,0.f}},
                       {{0.f,0.f,0.f,0.f},{0.f,0.f,0.f,0.f}}};
    const int nsteps = K >> 6;

    for (int ks = 0; ks < nsteps; ++ks) {
        const int b = ks & 1;
        const bool pf = (ks + 1 < nsteps);
        if (pf) {
            int ko = (ks + 1) << 6;
            ra0 = *(const s16x8*)(Aip0 + ko);
            ra1 = *(const s16x8*)(Aip1 + ko);
            rw0 = *(const s16x8*)(Wip0 + ko);
            rw1 = *(const s16x8*)(Wip1 + ko);
        }
#pragma unroll
        for (int sl = 0; sl < 2; ++sl) {
            s16x8 af0 = *(const s16x8*)&As[b][(32 * mh + c) * ASTR + sl * 32 + 8 * g];
            s16x8 af1 = *(const s16x8*)&As[b][(32 * mh + 16 + c) * ASTR + sl * 32 + 8 * g];
            s16x8 wf0 = *(const s16x8*)&Ws[b][(32 * nh + c) * ASTR + sl * 32 + 8 * g];
            s16x8 wf1 = *(const s16x8*)&Ws[b][(32 * nh + 16 + c) * ASTR + sl * 32 + 8 * g];
            acc[0][0] = __builtin_amdgcn_mfma_f32_16x16x32_bf16(af0, wf0, acc[0][0], 0, 0, 0);
            acc[0][1] = __builtin_amdgcn_mfma_f32_16x16x32_bf16(af0, wf1, acc[0][1], 0, 0, 0);
            acc[1][0] = __builtin_amdgcn_mfma_f32_16x16x32_bf16(af1, wf0, acc[1][0], 0, 0, 0);
            acc[1][1] = __builtin_amdgcn_mfma_f32_16x16x32_bf16(af1, wf1, acc[1][1], 0, 0, 0);
        }
        if (pf) {
            int nb = b ^ 1;
            *(s16x8*)&As[nb][srow * ASTR + cg8] = ra0;
            *(s16x8*)&As[nb][(32 + srow) * ASTR + cg8] = ra1;
            *(s16x8*)&Ws[nb][srow * ASTR + cg8] = rw0;
            *(s16x8*)&Ws[nb][(32 + srow) * ASTR + cg8] = rw1;
        }
        __syncthreads();
    }

#pragma unroll
    for (int i = 0; i < 2; ++i)
#pragma unroll
    for (int j = 0; j < 2; ++j) {
        int n = n0 + 32 * nh + 16 * j + c;
        float bv = bias[n];
        float sc = 1.f;
        if (EPI == 3) sc = (n < 256) ? 0.17677669529663687f : 1.f;
#pragma unroll
        for (int r = 0; r < 4; ++r) {
            int m = m0 + 32 * mh + 16 * i + 4 * g + r;
            float v = acc[i][j][r] + bv;
            if (EPI == 1) v = fmaxf(v, 0.f);
            if (EPI == 2) v += res[(size_t)m * N + n];
            if (EPI == 3) v *= sc;
            if (OUTBF) ((ushort_t*)outv)[(size_t)m * N + n] = f2bf(v);
            else ((float*)outv)[(size_t)m * N + n] = v;
        }
    }
}

// ---------------------------------------------------------------------------
// Split-KV MFMA flash attention (R5 skeleton + bitmask + VS=66 + bf16 Opart).
// lvl2: blocks 0..1023  = qt(32) x h(8) x split(4), tps=8
// lvl3: blocks 1024..1279 = qt(8) x h(8) x split(4), tps=2
// ---------------------------------------------------------------------------
#define QS 40
#define KS 40
#define VS 66    // 8 rows x 66 us = 264 dw = 8 mod 32 -> staging groups at banks 0/8/16/24
#define PS 72
#define OS 68

__global__ __launch_bounds__(256) void flash_split(const ushort_t* __restrict__ qkvb,
                                                   const u64* __restrict__ ubits,
                                                   ushort_t* __restrict__ Opart,
                                                   float2* __restrict__ ml) {
    __shared__ __align__(16) ushort_t qs[64 * QS];
    __shared__ __align__(16) ushort_t ks[2][64 * KS];
    __shared__ __align__(16) ushort_t vts[2][32 * VS];
    __shared__ __align__(16) char pso[64 * PS * 2];    // ps (bf16) / os (f32) alias
    ushort_t* ps = (ushort_t*)pso;
    float* os = (float*)pso;

    const int bx = blockIdx.x;
    int qt, h, split, L, sshift, rowbase, wpr;
    const u64* ub;
    if (bx < 1024) {
        qt = bx & 31; h = (bx >> 5) & 7; split = bx >> 8;
        L = 2048; sshift = 10; rowbase = 0; wpr = 32; ub = ubits;
    } else {
        int lo = bx - 1024;
        qt = lo & 7; h = (lo >> 3) & 7; split = lo >> 6;
        L = 512; sshift = 8; rowbase = 2048; wpr = 8; ub = ubits + 65536;
    }
    const int tps = (L >> 6) >> 2;
    const int ts0 = split * tps;

    const int t = threadIdx.x;
    const int w = t >> 6;
    const int l = t & 63;
    const int c = l & 15;
    const int g = l >> 4;
    const int smask = (1 << sshift) - 1;

    const int srow = t >> 2;
    const int sc8 = (t & 3) * 8;
    const int q0g = rowbase + qt * 64;

    *(s16x8*)&qs[srow * QS + sc8] =
        *(const s16x8*)&qkvb[(size_t)(q0g + srow) * 768 + h * 32 + sc8];

    {
        size_t base = (size_t)(rowbase + ts0 * 64 + srow) * 768 + h * 32 + sc8;
        s16x8 kreg = *(const s16x8*)&qkvb[base + 256];
        s16x8 vreg = *(const s16x8*)&qkvb[base + 512];
        *(s16x8*)&ks[0][srow * KS + sc8] = kreg;
#pragma unroll
        for (int i = 0; i < 8; ++i)
            vts[0][(sc8 + i) * VS + srow] = (ushort_t)vreg[i];
    }
    __syncthreads();

    const s16x8 qf = *(const s16x8*)&qs[(16 * w + c) * QS + 8 * g];
    const int ql = qt * 64 + 16 * w + c;
    const int qp = ql & smask, qfr = ql >> sshift;
    const u64* ubq = &ub[(size_t)ql * wpr];

    f32x4 oacc0 = {0.f, 0.f, 0.f, 0.f};
    f32x4 oacc1 = {0.f, 0.f, 0.f, 0.f};
    float mold = -3e38f, lrun = 0.f;
    const f32x4 zc = {0.f, 0.f, 0.f, 0.f};

    for (int kt = 0; kt < tps; ++kt) {
        const int bb = kt & 1;
        const int k0 = (ts0 + kt) << 6;
        const bool pf = (kt + 1 < tps);

        u64 wq = ubq[ts0 + kt];

        s16x8 kreg, vreg;
        if (pf) {
            size_t base = (size_t)(rowbase + k0 + 64 + srow) * 768 + h * 32 + sc8;
            kreg = *(const s16x8*)&qkvb[base + 256];
            vreg = *(const s16x8*)&qkvb[base + 512];
        }

        f32x4 sacc[4];
#pragma unroll
        for (int nt = 0; nt < 4; ++nt) {
            s16x8 kf = *(const s16x8*)&ks[bb][(16 * nt + c) * KS + 8 * g];
            sacc[nt] = __builtin_amdgcn_mfma_f32_16x16x32_bf16(kf, qf, zc, 0, 0, 0);
        }

        float sv[4][4];
        float m = -3e38f;
#pragma unroll
        for (int nt = 0; nt < 4; ++nt) {
            unsigned nib = (unsigned)(wq >> (16 * nt + 4 * g));
#pragma unroll
            for (int r = 0; r < 4; ++r) {
                int kg = k0 + 16 * nt + 4 * g + r;
                float s = sacc[nt][r]
                        + ((nib >> r) & 1 ? 1.f : 0.f)
                        + ((kg & smask) == qp ? 1.f : 0.f)
                        + ((kg >> sshift) == qfr ? 1.f : 0.f);
                sv[nt][r] = s;
                m = fmaxf(m, s);
            }
        }
        m = fmaxf(m, __shfl_xor(m, 16));
        m = fmaxf(m, __shfl_xor(m, 32));
        float newm = fmaxf(mold, m);
        float fac = __expf(mold - newm);
        mold = newm;

        float sum = 0.f;
#pragma unroll
        for (int nt = 0; nt < 4; ++nt) {
            float p0 = __expf(sv[nt][0] - newm);
            float p1 = __expf(sv[nt][1] - newm);
            float p2 = __expf(sv[nt][2] - newm);
            float p3 = __expf(sv[nt][3] - newm);
            sum += (p0 + p1) + (p2 + p3);
            u32x2 pk;
            pk[0] = ((unsigned)f2bf(p1) << 16) | f2bf(p0);
            pk[1] = ((unsigned)f2bf(p3) << 16) | f2bf(p2);
            *(u32x2*)&ps[(16 * w + c) * PS + 16 * nt + 4 * g] = pk;
        }
        sum += __shfl_xor(sum, 16);
        sum += __shfl_xor(sum, 32);
        lrun = lrun * fac + sum;
        oacc0 *= fac;
        oacc1 *= fac;

#pragma unroll
        for (int kc = 0; kc < 2; ++kc) {
            s16x8 pfr = *(const s16x8*)&ps[(16 * w + c) * PS + 32 * kc + 8 * g];
            s16x8 vf0 = *(const s16x8*)&vts[bb][c * VS + 32 * kc + 8 * g];
            s16x8 vf1 = *(const s16x8*)&vts[bb][(16 + c) * VS + 32 * kc + 8 * g];
            oacc0 = __builtin_amdgcn_mfma_f32_16x16x32_bf16(vf0, pfr, oacc0, 0, 0, 0);
            oacc1 = __builtin_amdgcn_mfma_f32_16x16x32_bf16(vf1, pfr, oacc1, 0, 0, 0);
        }

        __syncthreads();
        if (pf) {
            int nb = bb ^ 1;
            *(s16x8*)&ks[nb][srow * KS + sc8] = kreg;
#pragma unroll
            for (int i = 0; i < 8; ++i)
                vts[nb][(sc8 + i) * VS + srow] = (ushort_t)vreg[i];
        }
        __syncthreads();
    }

    if (g == 0) {
        int q = q0g + 16 * w + c;
        ml[((size_t)split * RTOT + q) * 8 + h] = make_float2(mold, lrun);
    }

    // unnormalized partial O (bf16) via LDS transpose
#pragma unroll
    for (int r = 0; r < 4; ++r) {
        os[(4 * g + r) * OS + 16 * w + c] = oacc0[r];
        os[(16 + 4 * g + r) * OS + 16 * w + c] = oacc1[r];
    }
    __syncthreads();
    {
        int r = t >> 2, d0 = (t & 3) * 8;
        s16x8 pk;
#pragma unroll
        for (int i = 0; i < 8; ++i) pk[i] = (short)f2bf(os[(d0 + i) * OS + r]);
        *(s16x8*)&Opart[((size_t)split * RTOT + q0g + r) * 256 + h * 32 + d0] = pk;
    }
}

// merge 4 split partials (bf16) -> bf16 attention output [2560,256]
__global__ __launch_bounds__(256) void flash_merge(const ushort_t* __restrict__ Opart,
                                                   const float2* __restrict__ ml,
                                                   ushort_t* __restrict__ obuf) {
    int r = blockIdx.x, t = threadIdx.x;
    int h = t >> 5;
    float2 m0 = ml[((size_t)0 * RTOT + r) * 8 + h];
    float2 m1 = ml[((size_t)1 * RTOT + r) * 8 + h];
    float2 m2 = ml[((size_t)2 * RTOT + r) * 8 + h];
    float2 m3 = ml[((size_t)3 * RTOT + r) * 8 + h];
    float ms = fmaxf(fmaxf(m0.x, m1.x), fmaxf(m2.x, m3.x));
    float w0 = __expf(m0.x - ms), w1 = __expf(m1.x - ms);
    float w2 = __expf(m2.x - ms), w3 = __expf(m3.x - ms);
    float denom = w0 * m0.y + w1 * m1.y + w2 * m2.y + w3 * m3.y;
    size_t idx = (size_t)r * 256 + t;
    const size_t stride = (size_t)RTOT * 256;
    float v = w0 * bf2f(Opart[idx]) + w1 * bf2f(Opart[idx + stride])
            + w2 * bf2f(Opart[idx + 2 * stride]) + w3 * bf2f(Opart[idx + 3 * stride]);
    obuf[idx] = f2bf(v / denom);
}

// LayerNorm over C=256, one block per row; optional bf16 copy
template <int WB>
__global__ __launch_bounds__(256) void ln_kernel(const float* __restrict__ in,
                                                 const float* __restrict__ g,
                                                 const float* __restrict__ b,
                                                 float* __restrict__ outf,
                                                 ushort_t* __restrict__ outb) {
    __shared__ float red[256];
    int row = blockIdx.x, t = threadIdx.x;
    float v = in[(size_t)row * 256 + t];
    red[t] = v;
    __syncthreads();
    for (int s = 128; s > 0; s >>= 1) {
        if (t < s) red[t] += red[t + s];
        __syncthreads();
    }
    float mean = red[0] * (1.f / 256.f);
    __syncthreads();
    float d = v - mean;
    red[t] = d * d;
    __syncthreads();
    for (int s = 128; s > 0; s >>= 1) {
        if (t < s) red[t] += red[t + s];
        __syncthreads();
    }
    float var = red[0] * (1.f / 256.f);
    float r = d * rsqrtf(var + 1e-5f) * g[t] + b[t];
    outf[(size_t)row * 256 + t] = r;
    if (WB) outb[(size_t)row * 256 + t] = f2bf(r);
}

// ---------------------------------------------------------------------------

extern "C" void kernel_launch(void* const* d_in, const int* in_sizes, int n_in,
                              void* d_out, int out_size, void* d_ws, size_t ws_size,
                              hipStream_t stream) {
    const float* f0 = (const float*)d_in[0];
    const float* f1 = (const float*)d_in[1];
    const float* f2 = (const float*)d_in[2];
    const float* f3 = (const float*)d_in[3];
    const float* u2 = (const float*)d_in[4];
    const float* u3 = (const float*)d_in[5];
    const float* Wqkv = (const float*)d_in[6];
    const float* bqkv = (const float*)d_in[7];
    const float* Wo   = (const float*)d_in[8];
    const float* bo   = (const float*)d_in[9];
    const float* g1   = (const float*)d_in[10];
    const float* b1   = (const float*)d_in[11];
    const float* Wfc1 = (const float*)d_in[12];
    const float* bfc1 = (const float*)d_in[13];
    const float* Wfc2 = (const float*)d_in[14];
    const float* bfc2 = (const float*)d_in[15];
    const float* g2   = (const float*)d_in[16];
    const float* b2   = (const float*)d_in[17];

    float* out = (float*)d_out;
    float* ws = (float*)d_ws;

    // bf16 weights
    ushort_t* wqkv = (ushort_t*)ws;             // 196608 us
    ushort_t* wo   = (ushort_t*)(ws + 98304);   // 65536 us
    ushort_t* wfc1 = (ushort_t*)(ws + 131072);  // 262144 us
    ushort_t* wfc2 = (ushort_t*)(ws + 262144);  // 262144 us

    // scratch (floats)
    float* sc = ws + 393216;
    float*    src_f32 = sc;                          // [0, 655360)
    ushort_t* qkvb    = (ushort_t*)(sc + 655360);    // 2560*768 us -> ends 1638400
    ushort_t* obuf    = (ushort_t*)(sc + 1638400);   // 2560*256 us (src_bf alias)
    ushort_t* src_bf  = obuf;
    float*    t1      = sc + 1966080;                // 655360
    float*    x_f32   = sc + 2621440;                // 655360 (ubits alias)
    u64*      ubits   = (u64*)x_f32;                 // 69632 u64 = 139264 f
    ushort_t* x_bf    = (ushort_t*)(sc + 3276800);   // 2560*256 us -> ends 3604480
    float2*   ml      = (float2*)(sc + 3604480);     // 4*2560*8 f2 = 163840 f
    ushort_t* Opart   = (ushort_t*)(sc + 3768320);   // 4*2560*256 us = 1310720 f
    ushort_t* h_bf    = Opart;                       // 2560*1024 us (alias, post-merge)
    float*    y       = src_f32;

    prep<<<20736, 256, 0, stream>>>(Wqkv, Wo, Wfc1, Wfc2, wqkv, wo, wfc1, wfc2,
                                    u2, u3, ubits, f2, f3, src_f32, src_bf);

    hipMemcpyAsync(out, f0, (size_t)3276800 * 4, hipMemcpyDeviceToDevice, stream);
    hipMemcpyAsync(out + 3276800, f1, (size_t)819200 * 4, hipMemcpyDeviceToDevice, stream);

    gemm64<3, 1><<<dim3(12, 40), 256, 0, stream>>>(
        src_bf, wqkv, bqkv, nullptr, qkvb, RTOT, 768, 256);
    flash_split<<<1280, 256, 0, stream>>>(qkvb, ubits, Opart, ml);
    flash_merge<<<2560, 256, 0, stream>>>(Opart, ml, obuf);
    gemm32<2, 0><<<dim3(8, 80), 128, 0, stream>>>(
        obuf, wo, bo, src_f32, t1, RTOT, 256, 256);
    ln_kernel<1><<<2560, 256, 0, stream>>>(t1, g1, b1, x_f32, x_bf);
    gemm64<1, 1><<<dim3(16, 40), 256, 0, stream>>>(
        x_bf, wfc1, bfc1, nullptr, h_bf, RTOT, 1024, 256);
    gemm32<2, 0><<<dim3(8, 80), 128, 0, stream>>>(
        h_bf, wfc2, bfc2, x_f32, t1, RTOT, 256, 1024);
    ln_kernel<0><<<2560, 256, 0, stream>>>(t1, g2, b2, y, nullptr);
    lc_out<<<2560, 256, 0, stream>>>(y, out + 4096000, out + 4620288);
}